// Round 1
// baseline (1995.117 us; speedup 1.0000x reference)
//
#include <hip/hip_runtime.h>
#include <math.h>

#define SS 2048
#define DD 1280
#define HH 16
#define HDD 80
#define ND3 3840

// ---------------- GEMM: C[M][N] = A[M][K] @ B[N][K]^T + bias[N] ----------------
#define BM 64
#define BN 64
#define BK 16

__global__ __launch_bounds__(256) void gemm_nt_bias(
    const float* __restrict__ A, const float* __restrict__ B,
    const float* __restrict__ bias, float* __restrict__ C,
    int M, int N, int K)
{
    // LDS stored transposed: As[kk][m], Bs[kk][n] so the inner loop reads are b128
    __shared__ float As[BK][BM];
    __shared__ float Bs[BK][BN];
    const int tid = threadIdx.x;
    const int bm = blockIdx.y * BM;
    const int bn = blockIdx.x * BN;
    const int tm = (tid >> 4) << 2;   // 0,4,...,60
    const int tn = (tid & 15) << 2;   // 0,4,...,60
    const int lr = tid >> 2;          // 0..63
    const int lc = (tid & 3) << 2;    // 0,4,8,12
    float c[4][4] = {{0.f}};
    const float* ap = A + (size_t)(bm + lr) * K + lc;
    const float* bp = B + (size_t)(bn + lr) * K + lc;
    for (int k0 = 0; k0 < K; k0 += BK) {
        float4 av = *(const float4*)(ap + k0);
        float4 bv = *(const float4*)(bp + k0);
        __syncthreads();
        As[lc+0][lr] = av.x; As[lc+1][lr] = av.y; As[lc+2][lr] = av.z; As[lc+3][lr] = av.w;
        Bs[lc+0][lr] = bv.x; Bs[lc+1][lr] = bv.y; Bs[lc+2][lr] = bv.z; Bs[lc+3][lr] = bv.w;
        __syncthreads();
        #pragma unroll
        for (int kk = 0; kk < BK; ++kk) {
            float4 a = *(const float4*)&As[kk][tm];
            float4 b = *(const float4*)&Bs[kk][tn];
            c[0][0] += a.x*b.x; c[0][1] += a.x*b.y; c[0][2] += a.x*b.z; c[0][3] += a.x*b.w;
            c[1][0] += a.y*b.x; c[1][1] += a.y*b.y; c[1][2] += a.y*b.z; c[1][3] += a.y*b.w;
            c[2][0] += a.z*b.x; c[2][1] += a.z*b.y; c[2][2] += a.z*b.z; c[2][3] += a.z*b.w;
            c[3][0] += a.w*b.x; c[3][1] += a.w*b.y; c[3][2] += a.w*b.z; c[3][3] += a.w*b.w;
        }
    }
    float4 bb = *(const float4*)&bias[bn + tn];
    #pragma unroll
    for (int i = 0; i < 4; ++i) {
        float4 o;
        o.x = c[i][0] + bb.x; o.y = c[i][1] + bb.y;
        o.z = c[i][2] + bb.z; o.w = c[i][3] + bb.w;
        *(float4*)&C[(size_t)(bm + tm + i) * N + bn + tn] = o;
    }
}

// ---------------- RoPE + scatter qkv[s][3*D] -> q/k/v [H][S][HD] ----------------
__global__ __launch_bounds__(256) void rope_scatter(
    const float* __restrict__ qkv, const float* __restrict__ rpe,
    float* __restrict__ q, float* __restrict__ k, float* __restrict__ v)
{
    const int s = blockIdx.x;
    for (int j = threadIdx.x; j < ND3; j += 256) {
        int p = j / DD;
        int rem = j - p * DD;
        int hh = rem / HDD;
        int d = rem - hh * HDD;
        float x = qkv[(size_t)s * ND3 + j];
        float val;
        if (p == 2) {
            val = x;
        } else {
            int dm = (d < 40) ? d : d - 40;
            float ang = rpe[s * 40 + dm];
            float cs = cosf(ang), sn = sinf(ang);
            float other = (d < 40)
                ? -qkv[(size_t)s * ND3 + p * DD + hh * HDD + d + 40]
                :  qkv[(size_t)s * ND3 + p * DD + hh * HDD + d - 40];
            val = x * cs + other * sn;
        }
        float* dst = (p == 0) ? q : (p == 1) ? k : v;
        dst[((size_t)hh * SS + s) * HDD + d] = val;
    }
}

// ---------------- attention: one wave per query row, LDS-staged K/V tiles ------
__global__ __launch_bounds__(256) void attn_kernel(
    const float* __restrict__ q, const float* __restrict__ k,
    const float* __restrict__ v, float* __restrict__ out)
{
    __shared__ float sc[4][SS];      // 32 KB scores (one row per wave)
    __shared__ float kt[64][84];     // 21.5 KB K/V tile (84: 16B-aligned rows, bank-spread)
    __shared__ float qr[4][84];      // q rows
    const int h = blockIdx.y;
    const int tid = threadIdx.x;
    const int w = tid >> 6;
    const int lane = tid & 63;
    const int qi0 = blockIdx.x << 2;
    const int qi = qi0 + w;
    const float scale = 0.11180339887498949f;  // 80^-0.5

    for (int i = tid; i < 4 * HDD; i += 256) {
        int ww = i / HDD, d = i - ww * HDD;
        qr[ww][d] = q[((size_t)h * SS + qi0 + ww) * HDD + d];
    }

    const float* kbase = k + (size_t)h * SS * HDD;
    const float* vbase = v + (size_t)h * SS * HDD;

    float m = -1e30f;
    for (int t = 0; t < SS; t += 64) {
        __syncthreads();
        #pragma unroll
        for (int u = 0; u < 5; ++u) {
            int i4 = tid + 256 * u;               // 0..1279 -> 64 rows x 20 float4
            int kk = i4 / 20, d4 = (i4 - kk * 20) * 4;
            *(float4*)&kt[kk][d4] = *(const float4*)(kbase + (size_t)(t + kk) * HDD + d4);
        }
        __syncthreads();
        float s = 0.f;
        #pragma unroll
        for (int d4 = 0; d4 < HDD; d4 += 4) {
            float4 a = *(const float4*)&qr[w][d4];
            float4 b = *(const float4*)&kt[lane][d4];
            s += a.x*b.x + a.y*b.y + a.z*b.z + a.w*b.w;
        }
        s *= scale;
        sc[w][t + lane] = s;
        m = fmaxf(m, s);
    }
    #pragma unroll
    for (int off = 32; off > 0; off >>= 1) m = fmaxf(m, __shfl_xor(m, off, 64));
    __syncthreads();   // make sc row visible across the wave's lanes
    float sum = 0.f;
    for (int kk = lane; kk < SS; kk += 64) {
        float e = expf(sc[w][kk] - m);
        sc[w][kk] = e;
        sum += e;
    }
    #pragma unroll
    for (int off = 32; off > 0; off >>= 1) sum += __shfl_xor(sum, off, 64);
    float inv = 1.f / sum;

    float acc0 = 0.f, acc1 = 0.f;
    for (int t = 0; t < SS; t += 64) {
        __syncthreads();
        #pragma unroll
        for (int u = 0; u < 5; ++u) {
            int i4 = tid + 256 * u;
            int kk = i4 / 20, d4 = (i4 - kk * 20) * 4;
            *(float4*)&kt[kk][d4] = *(const float4*)(vbase + (size_t)(t + kk) * HDD + d4);
        }
        __syncthreads();
        #pragma unroll 8
        for (int kkl = 0; kkl < 64; ++kkl) {
            float p = sc[w][t + kkl];
            acc0 += p * kt[kkl][lane];
            acc1 += p * kt[kkl][64 + (lane & 15)];
        }
    }
    out[(size_t)qi * DD + h * HDD + lane] = acc0 * inv;
    if (lane < 16)
        out[(size_t)qi * DD + h * HDD + 64 + lane] = acc1 * inv;
}

extern "C" void kernel_launch(void* const* d_in, const int* in_sizes, int n_in,
                              void* d_out, int out_size, void* d_ws, size_t ws_size,
                              hipStream_t stream)
{
    const float* hs     = (const float*)d_in[0];
    const float* rpe    = (const float*)d_in[1];
    const float* qkv_w  = (const float*)d_in[2];
    const float* qkv_b  = (const float*)d_in[3];
    const float* proj_w = (const float*)d_in[4];
    const float* proj_b = (const float*)d_in[5];
    float* out = (float*)d_out;

    float* w = (float*)d_ws;
    float* qkv_buf = w;                              // 2048*3840 floats
    float* qb = w + (size_t)SS * ND3;
    float* kb = qb + (size_t)HH * SS * HDD;
    float* vb = kb + (size_t)HH * SS * HDD;
    float* attn_out = w;                             // aliases qkv_buf (dead after rope)

    gemm_nt_bias<<<dim3(ND3 / BN, SS / BM), 256, 0, stream>>>(hs, qkv_w, qkv_b, qkv_buf, SS, ND3, DD);
    rope_scatter<<<dim3(SS), 256, 0, stream>>>(qkv_buf, rpe, qb, kb, vb);
    attn_kernel<<<dim3(SS / 4, HH), 256, 0, stream>>>(qb, kb, vb, attn_out);
    gemm_nt_bias<<<dim3(DD / BN, SS / BM), 256, 0, stream>>>(attn_out, proj_w, proj_b, out, SS, DD, DD);
}

// Round 2
// 695.651 us; speedup vs baseline: 2.8680x; 2.8680x over previous
//
#include <hip/hip_runtime.h>
#include <math.h>

#define SS 2048
#define DD 1280
#define HH 16
#define HDD 80
#define ND3 3840

typedef __attribute__((ext_vector_type(8))) short short8;
typedef __attribute__((ext_vector_type(4))) float f32x4;

__device__ inline short f2bf(float f) {
    union { float f; unsigned u; } x; x.f = f;
    unsigned r = x.u + 0x7FFF + ((x.u >> 16) & 1);
    return (short)(r >> 16);
}

// ---------------- GEMM: C[M][N] = A[M][K] @ B[N][K]^T + bias[N] ----------------
#define BM 64
#define BN 64
#define BK 16

__global__ __launch_bounds__(256) void gemm_nt_bias(
    const float* __restrict__ A, const float* __restrict__ B,
    const float* __restrict__ bias, float* __restrict__ C,
    int M, int N, int K)
{
    __shared__ float As[BK][BM];
    __shared__ float Bs[BK][BN];
    const int tid = threadIdx.x;
    const int bm = blockIdx.y * BM;
    const int bn = blockIdx.x * BN;
    const int tm = (tid >> 4) << 2;
    const int tn = (tid & 15) << 2;
    const int lr = tid >> 2;
    const int lc = (tid & 3) << 2;
    float c[4][4] = {{0.f}};
    const float* ap = A + (size_t)(bm + lr) * K + lc;
    const float* bp = B + (size_t)(bn + lr) * K + lc;
    for (int k0 = 0; k0 < K; k0 += BK) {
        float4 av = *(const float4*)(ap + k0);
        float4 bv = *(const float4*)(bp + k0);
        __syncthreads();
        As[lc+0][lr] = av.x; As[lc+1][lr] = av.y; As[lc+2][lr] = av.z; As[lc+3][lr] = av.w;
        Bs[lc+0][lr] = bv.x; Bs[lc+1][lr] = bv.y; Bs[lc+2][lr] = bv.z; Bs[lc+3][lr] = bv.w;
        __syncthreads();
        #pragma unroll
        for (int kk = 0; kk < BK; ++kk) {
            float4 a = *(const float4*)&As[kk][tm];
            float4 b = *(const float4*)&Bs[kk][tn];
            c[0][0] += a.x*b.x; c[0][1] += a.x*b.y; c[0][2] += a.x*b.z; c[0][3] += a.x*b.w;
            c[1][0] += a.y*b.x; c[1][1] += a.y*b.y; c[1][2] += a.y*b.z; c[1][3] += a.y*b.w;
            c[2][0] += a.z*b.x; c[2][1] += a.z*b.y; c[2][2] += a.z*b.z; c[2][3] += a.z*b.w;
            c[3][0] += a.w*b.x; c[3][1] += a.w*b.y; c[3][2] += a.w*b.z; c[3][3] += a.w*b.w;
        }
    }
    float4 bb = *(const float4*)&bias[bn + tn];
    #pragma unroll
    for (int i = 0; i < 4; ++i) {
        float4 o;
        o.x = c[i][0] + bb.x; o.y = c[i][1] + bb.y;
        o.z = c[i][2] + bb.z; o.w = c[i][3] + bb.w;
        *(float4*)&C[(size_t)(bm + tm + i) * N + bn + tn] = o;
    }
}

// ---------------- RoPE + scatter qkv[s][3*D] -> q/k/v [H][S][HD] ----------------
__global__ __launch_bounds__(256) void rope_scatter(
    const float* __restrict__ qkv, const float* __restrict__ rpe,
    float* __restrict__ q, float* __restrict__ k, float* __restrict__ v)
{
    const int s = blockIdx.x;
    for (int j = threadIdx.x; j < ND3; j += 256) {
        int p = j / DD;
        int rem = j - p * DD;
        int hh = rem / HDD;
        int d = rem - hh * HDD;
        float x = qkv[(size_t)s * ND3 + j];
        float val;
        if (p == 2) {
            val = x;
        } else {
            int dm = (d < 40) ? d : d - 40;
            float ang = rpe[s * 40 + dm];
            float cs = cosf(ang), sn = sinf(ang);
            float other = (d < 40)
                ? -qkv[(size_t)s * ND3 + p * DD + hh * HDD + d + 40]
                :  qkv[(size_t)s * ND3 + p * DD + hh * HDD + d - 40];
            val = x * cs + other * sn;
        }
        float* dst = (p == 0) ? q : (p == 1) ? k : v;
        dst[((size_t)hh * SS + s) * HDD + d] = val;
    }
}

// ---------------- flash attention, bf16 MFMA 16x16x32 ----------------
// block: 4 waves, 64 q-rows (16/wave); K-tile 64; HD 80 padded to 96.
__global__ __launch_bounds__(256) void attn_mfma(
    const float* __restrict__ q, const float* __restrict__ k,
    const float* __restrict__ v, float* __restrict__ out)
{
    __shared__ short Ks[64][104];    // k-positions x d (bf16), pad cols 80..95 zeroed
    __shared__ short Vts[80][72];    // d x k-positions (transposed V)
    __shared__ short Ps[4][16][72];  // per-wave P tile: 16 rows x 64 k-positions

    const int h = blockIdx.y;
    const int q0 = blockIdx.x << 6;
    const int tid = threadIdx.x;
    const int w = tid >> 6;
    const int lane = tid & 63;
    const int l15 = lane & 15;
    const int quad = lane >> 4;
    const float scale = 0.11180339887498949f;  // 80^-0.5

    const float* qbase = q + (size_t)h * SS * HDD;
    const float* kbase = k + (size_t)h * SS * HDD;
    const float* vbase = v + (size_t)h * SS * HDD;

    // ---- load Q fragments (A-operand), scale folded, pad d>=80 with zero ----
    short8 qf[3];
    {
        const int row = q0 + w * 16 + l15;
        #pragma unroll
        for (int kk = 0; kk < 3; ++kk) {
            int c0 = kk * 32 + quad * 8;
            short8 f;
            if (c0 < HDD) {
                float4 a = *(const float4*)(qbase + (size_t)row * HDD + c0);
                float4 b = *(const float4*)(qbase + (size_t)row * HDD + c0 + 4);
                f[0] = f2bf(a.x * scale); f[1] = f2bf(a.y * scale);
                f[2] = f2bf(a.z * scale); f[3] = f2bf(a.w * scale);
                f[4] = f2bf(b.x * scale); f[5] = f2bf(b.y * scale);
                f[6] = f2bf(b.z * scale); f[7] = f2bf(b.w * scale);
            } else {
                f = (short8)0;
            }
            qf[kk] = f;
        }
    }

    // zero the K pad columns once (cols 80..95)
    if (tid < 128) {
        int r = tid >> 1, c = 80 + (tid & 1) * 8;
        *(short8*)&Ks[r][c] = (short8)0;
    }

    float mrun[4], lrun[4];
    f32x4 o[5];
    #pragma unroll
    for (int r = 0; r < 4; ++r) { mrun[r] = -1e30f; lrun[r] = 0.f; }
    #pragma unroll
    for (int n = 0; n < 5; ++n) o[n] = (f32x4){0.f, 0.f, 0.f, 0.f};

    for (int kt = 0; kt < SS; kt += 64) {
        __syncthreads();   // prev tile fully consumed (and pad-zero visible, 1st iter)

        // ---- stage K tile: 64 rows x 80 cols, bf16, natural layout ----
        #pragma unroll
        for (int u = 0; u < 3; ++u) {
            int i = tid + u * 256;
            if (i < 640) {
                int r = i / 10, c = (i - r * 10) * 8;
                const float* kp = kbase + (size_t)(kt + r) * HDD + c;
                float4 a = *(const float4*)kp;
                float4 b = *(const float4*)(kp + 4);
                short8 f;
                f[0]=f2bf(a.x); f[1]=f2bf(a.y); f[2]=f2bf(a.z); f[3]=f2bf(a.w);
                f[4]=f2bf(b.x); f[5]=f2bf(b.y); f[6]=f2bf(b.z); f[7]=f2bf(b.w);
                *(short8*)&Ks[r][c] = f;
            }
        }
        // ---- stage V tile transposed: Vts[d][kpos] ----
        #pragma unroll
        for (int u = 0; u < 5; ++u) {
            int i = tid + u * 256;
            int r = i & 63, c4 = (i >> 6) * 4;
            float4 a = *(const float4*)(vbase + (size_t)(kt + r) * HDD + c4);
            Vts[c4+0][r] = f2bf(a.x);
            Vts[c4+1][r] = f2bf(a.y);
            Vts[c4+2][r] = f2bf(a.z);
            Vts[c4+3][r] = f2bf(a.w);
        }
        __syncthreads();

        // ---- QK^T: S[16 x 64] per wave ----
        f32x4 s[4];
        #pragma unroll
        for (int nt = 0; nt < 4; ++nt) {
            f32x4 acc = (f32x4){0.f, 0.f, 0.f, 0.f};
            #pragma unroll
            for (int kk = 0; kk < 3; ++kk) {
                short8 bf = *(short8*)&Ks[nt * 16 + l15][kk * 32 + quad * 8];
                acc = __builtin_amdgcn_mfma_f32_16x16x32_bf16(qf[kk], bf, acc, 0, 0, 0);
            }
            s[nt] = acc;
        }

        // ---- online softmax (row = quad*4 + reg, col = nt*16 + l15) ----
        float alpha[4], rsum[4], mnew[4];
        #pragma unroll
        for (int r = 0; r < 4; ++r) {
            float tm = fmaxf(fmaxf(s[0][r], s[1][r]), fmaxf(s[2][r], s[3][r]));
            #pragma unroll
            for (int off = 1; off < 16; off <<= 1)
                tm = fmaxf(tm, __shfl_xor(tm, off, 64));
            mnew[r] = fmaxf(mrun[r], tm);
            alpha[r] = __expf(mrun[r] - mnew[r]);
            mrun[r] = mnew[r];
            rsum[r] = 0.f;
        }
        #pragma unroll
        for (int nt = 0; nt < 4; ++nt) {
            #pragma unroll
            for (int r = 0; r < 4; ++r) {
                float p = __expf(s[nt][r] - mnew[r]);
                rsum[r] += p;
                Ps[w][quad * 4 + r][nt * 16 + l15] = f2bf(p);
            }
        }
        #pragma unroll
        for (int r = 0; r < 4; ++r) {
            float rs = rsum[r];
            #pragma unroll
            for (int off = 1; off < 16; off <<= 1)
                rs += __shfl_xor(rs, off, 64);
            lrun[r] = lrun[r] * alpha[r] + rs;
        }
        #pragma unroll
        for (int n = 0; n < 5; ++n)
            #pragma unroll
            for (int r = 0; r < 4; ++r)
                o[n][r] *= alpha[r];

        // ---- P (C-layout) -> A-operand via LDS, then PV ----
        short8 pf[2];
        #pragma unroll
        for (int kk = 0; kk < 2; ++kk)
            pf[kk] = *(short8*)&Ps[w][l15][kk * 32 + quad * 8];
        #pragma unroll
        for (int n = 0; n < 5; ++n) {
            #pragma unroll
            for (int kk = 0; kk < 2; ++kk) {
                short8 vf = *(short8*)&Vts[n * 16 + l15][kk * 32 + quad * 8];
                o[n] = __builtin_amdgcn_mfma_f32_16x16x32_bf16(pf[kk], vf, o[n], 0, 0, 0);
            }
        }
    }

    // ---- epilogue: divide by l, store ----
    float inv[4];
    #pragma unroll
    for (int r = 0; r < 4; ++r) inv[r] = 1.f / lrun[r];
    #pragma unroll
    for (int n = 0; n < 5; ++n) {
        #pragma unroll
        for (int r = 0; r < 4; ++r) {
            int row = q0 + w * 16 + quad * 4 + r;
            out[(size_t)row * DD + h * HDD + n * 16 + l15] = o[n][r] * inv[r];
        }
    }
}

extern "C" void kernel_launch(void* const* d_in, const int* in_sizes, int n_in,
                              void* d_out, int out_size, void* d_ws, size_t ws_size,
                              hipStream_t stream)
{
    const float* hs     = (const float*)d_in[0];
    const float* rpe    = (const float*)d_in[1];
    const float* qkv_w  = (const float*)d_in[2];
    const float* qkv_b  = (const float*)d_in[3];
    const float* proj_w = (const float*)d_in[4];
    const float* proj_b = (const float*)d_in[5];
    float* out = (float*)d_out;

    float* w = (float*)d_ws;
    float* qkv_buf = w;                              // 2048*3840 floats
    float* qb = w + (size_t)SS * ND3;
    float* kb = qb + (size_t)HH * SS * HDD;
    float* vb = kb + (size_t)HH * SS * HDD;
    float* attn_out = w;                             // aliases qkv_buf (dead after rope)

    gemm_nt_bias<<<dim3(ND3 / BN, SS / BM), 256, 0, stream>>>(hs, qkv_w, qkv_b, qkv_buf, SS, ND3, DD);
    rope_scatter<<<dim3(SS), 256, 0, stream>>>(qkv_buf, rpe, qb, kb, vb);
    attn_mfma<<<dim3(SS / 64, HH), 256, 0, stream>>>(qb, kb, vb, attn_out);
    gemm_nt_bias<<<dim3(DD / BN, SS / BM), 256, 0, stream>>>(attn_out, proj_w, proj_b, out, SS, DD, DD);
}

// Round 3
// 300.472 us; speedup vs baseline: 6.6399x; 2.3152x over previous
//
#include <hip/hip_runtime.h>
#include <math.h>

#define SS 2048
#define DD 1280
#define HH 16
#define HDD 80
#define ND3 3840

typedef __attribute__((ext_vector_type(8))) short short8;
typedef __attribute__((ext_vector_type(4))) short s16x4;
typedef __attribute__((ext_vector_type(4))) float f32x4;

__device__ inline short f2bf(float f) {
    union { float f; unsigned u; } x; x.f = f;
    unsigned r = x.u + 0x7FFF + ((x.u >> 16) & 1);
    return (short)(r >> 16);
}
__device__ inline float bf2f(short s) {
    union { unsigned u; float f; } x; x.u = ((unsigned)(unsigned short)s) << 16;
    return x.f;
}

// ---------------- split fp32 -> (hi, lo) bf16 ----------------
__global__ __launch_bounds__(256) void split_hl(
    const float* __restrict__ x, short* __restrict__ hi, short* __restrict__ lo, int n)
{
    int i = (blockIdx.x * 256 + threadIdx.x) * 4;
    if (i >= n) return;
    float4 v = *(const float4*)(x + i);
    s16x4 h, l;
    float vv[4] = {v.x, v.y, v.z, v.w};
    #pragma unroll
    for (int c = 0; c < 4; ++c) {
        short hh = f2bf(vv[c]);
        h[c] = hh;
        l[c] = f2bf(vv[c] - bf2f(hh));
    }
    *(s16x4*)(hi + i) = h;
    *(s16x4*)(lo + i) = l;
}

// ---------------- bf16x3 MFMA GEMM: C = A @ B^T + bias ----------------
// A (hi/lo) [M][K] bf16, B (hi/lo) [N][K] bf16, C [M][N] fp32.
// Block 256 thr = 4 waves (2x2), tile 128 x BNT, BK=32.
#define LDSA(m, kg) ((m) * 32 + (((kg) ^ (((m) >> 1) & 3)) << 3))

template <int BNT>
__global__ __launch_bounds__(256) void gemm_bf16x3(
    const short* __restrict__ Ah, const short* __restrict__ Al,
    const short* __restrict__ Bh, const short* __restrict__ Bl,
    const float* __restrict__ bias, float* __restrict__ C,
    int M, int N, int K)
{
    constexpr int JT = BNT / 32;        // n-tiles per wave
    constexpr int BU = (BNT * 4) / 256; // B staging chunks per thread
    __shared__ short AhS[128 * 32];
    __shared__ short AlS[128 * 32];
    __shared__ short BhS[BNT * 32];
    __shared__ short BlS[BNT * 32];

    const int tid = threadIdx.x;
    const int w = tid >> 6;
    const int lane = tid & 63;
    const int l15 = lane & 15;
    const int quad = lane >> 4;
    const int wm = w >> 1, wn = w & 1;
    const int bm = blockIdx.y * 128;
    const int bn = blockIdx.x * BNT;

    f32x4 acc[4][JT];
    #pragma unroll
    for (int i = 0; i < 4; ++i)
        #pragma unroll
        for (int j = 0; j < JT; ++j)
            acc[i][j] = (f32x4){0.f, 0.f, 0.f, 0.f};

    short8 rah[2], ral[2], rbh[BU], rbl[BU];
    auto loadg = [&](int k0) {
        #pragma unroll
        for (int u = 0; u < 2; ++u) {
            int c = tid + u * 256, m = c >> 2, kg = c & 3;
            size_t off = (size_t)(bm + m) * K + k0 + kg * 8;
            rah[u] = *(const short8*)(Ah + off);
            ral[u] = *(const short8*)(Al + off);
        }
        #pragma unroll
        for (int u = 0; u < BU; ++u) {
            int c = tid + u * 256, m = c >> 2, kg = c & 3;
            size_t off = (size_t)(bn + m) * K + k0 + kg * 8;
            rbh[u] = *(const short8*)(Bh + off);
            rbl[u] = *(const short8*)(Bl + off);
        }
    };

    loadg(0);
    for (int k0 = 0; k0 < K; k0 += 32) {
        __syncthreads();
        #pragma unroll
        for (int u = 0; u < 2; ++u) {
            int c = tid + u * 256, m = c >> 2, kg = c & 3;
            *(short8*)&AhS[LDSA(m, kg)] = rah[u];
            *(short8*)&AlS[LDSA(m, kg)] = ral[u];
        }
        #pragma unroll
        for (int u = 0; u < BU; ++u) {
            int c = tid + u * 256, m = c >> 2, kg = c & 3;
            *(short8*)&BhS[LDSA(m, kg)] = rbh[u];
            *(short8*)&BlS[LDSA(m, kg)] = rbl[u];
        }
        __syncthreads();
        if (k0 + 32 < K) loadg(k0 + 32);

        short8 af[4], alf[4], bfh[JT], bfl[JT];
        #pragma unroll
        for (int i = 0; i < 4; ++i) {
            int m = wm * 64 + i * 16 + l15;
            af[i]  = *(short8*)&AhS[LDSA(m, quad)];
            alf[i] = *(short8*)&AlS[LDSA(m, quad)];
        }
        #pragma unroll
        for (int j = 0; j < JT; ++j) {
            int n = wn * (BNT / 2) + j * 16 + l15;
            bfh[j] = *(short8*)&BhS[LDSA(n, quad)];
            bfl[j] = *(short8*)&BlS[LDSA(n, quad)];
        }
        #pragma unroll
        for (int i = 0; i < 4; ++i)
            #pragma unroll
            for (int j = 0; j < JT; ++j) {
                acc[i][j] = __builtin_amdgcn_mfma_f32_16x16x32_bf16(af[i],  bfh[j], acc[i][j], 0, 0, 0);
                acc[i][j] = __builtin_amdgcn_mfma_f32_16x16x32_bf16(af[i],  bfl[j], acc[i][j], 0, 0, 0);
                acc[i][j] = __builtin_amdgcn_mfma_f32_16x16x32_bf16(alf[i], bfh[j], acc[i][j], 0, 0, 0);
            }
    }

    #pragma unroll
    for (int j = 0; j < JT; ++j) {
        int col = bn + wn * (BNT / 2) + j * 16 + l15;
        float bb = bias[col];
        #pragma unroll
        for (int i = 0; i < 4; ++i)
            #pragma unroll
            for (int r = 0; r < 4; ++r) {
                int row = bm + wm * 64 + i * 16 + quad * 4 + r;
                C[(size_t)row * N + col] = acc[i][j][r] + bb;
            }
    }
}

// ---------------- RoPE + scatter -> bf16 q (pre-scaled), k, v ----------------
__global__ __launch_bounds__(256) void rope_scatter_bf16(
    const float* __restrict__ qkv, const float* __restrict__ rpe,
    short* __restrict__ q, short* __restrict__ k, short* __restrict__ v)
{
    __shared__ float cs[40], sn[40];
    const int s = blockIdx.x;
    if (threadIdx.x < 40)
        __sincosf(rpe[s * 40 + threadIdx.x], &sn[threadIdx.x], &cs[threadIdx.x]);
    __syncthreads();
    const float scale = 0.11180339887498949f;  // 80^-0.5
    for (int j = threadIdx.x; j < ND3; j += 256) {
        int p = j / DD;
        int rem = j - p * DD;
        int hh = rem / HDD;
        int d = rem - hh * HDD;
        float x = qkv[(size_t)s * ND3 + j];
        float val;
        if (p == 2) {
            val = x;
        } else {
            int dm = (d < 40) ? d : d - 40;
            float other = (d < 40)
                ? -qkv[(size_t)s * ND3 + p * DD + hh * HDD + d + 40]
                :  qkv[(size_t)s * ND3 + p * DD + hh * HDD + d - 40];
            val = x * cs[dm] + other * sn[dm];
            if (p == 0) val *= scale;
        }
        short* dst = (p == 0) ? q : (p == 1) ? k : v;
        dst[((size_t)hh * SS + s) * HDD + d] = f2bf(val);
    }
}

// ---------------- flash attention, bf16 MFMA, bf16 inputs, hi/lo output ------
__global__ __launch_bounds__(256) void attn_mfma(
    const short* __restrict__ q, const short* __restrict__ k,
    const short* __restrict__ v, short* __restrict__ out_hi,
    short* __restrict__ out_lo)
{
    __shared__ short Ks[64][104];    // k-positions x d, pad cols 80..95 zeroed
    __shared__ short Vts[80][72];    // d x k-positions (transposed V)
    __shared__ short Ps[4][16][72];  // per-wave P tile

    const int h = blockIdx.y;
    const int q0 = blockIdx.x << 6;
    const int tid = threadIdx.x;
    const int w = tid >> 6;
    const int lane = tid & 63;
    const int l15 = lane & 15;
    const int quad = lane >> 4;

    const short* qbase = q + (size_t)h * SS * HDD;
    const short* kbase = k + (size_t)h * SS * HDD;
    const short* vbase = v + (size_t)h * SS * HDD;

    // Q fragments (A-operand); q is pre-scaled bf16
    short8 qf[3];
    {
        const int row = q0 + w * 16 + l15;
        #pragma unroll
        for (int kk = 0; kk < 3; ++kk) {
            int c0 = kk * 32 + quad * 8;
            qf[kk] = (c0 < HDD) ? *(const short8*)(qbase + (size_t)row * HDD + c0)
                                : (short8)0;
        }
    }

    if (tid < 128) {  // zero K pad cols 80..95
        int r = tid >> 1, c = 80 + (tid & 1) * 8;
        *(short8*)&Ks[r][c] = (short8)0;
    }

    float mrun[4], lrun[4];
    f32x4 o[5];
    #pragma unroll
    for (int r = 0; r < 4; ++r) { mrun[r] = -1e30f; lrun[r] = 0.f; }
    #pragma unroll
    for (int n = 0; n < 5; ++n) o[n] = (f32x4){0.f, 0.f, 0.f, 0.f};

    for (int kt = 0; kt < SS; kt += 64) {
        __syncthreads();
        #pragma unroll
        for (int u = 0; u < 3; ++u) {
            int i = tid + u * 256;
            if (i < 640) {
                int r = i / 10, c = (i - r * 10) * 8;
                *(short8*)&Ks[r][c] = *(const short8*)(kbase + (size_t)(kt + r) * HDD + c);
            }
        }
        #pragma unroll
        for (int u = 0; u < 5; ++u) {
            int i4 = tid + u * 256;
            int r = i4 & 63, c4 = (i4 >> 6) * 4;
            s16x4 a = *(const s16x4*)(vbase + (size_t)(kt + r) * HDD + c4);
            Vts[c4 + 0][r] = a[0];
            Vts[c4 + 1][r] = a[1];
            Vts[c4 + 2][r] = a[2];
            Vts[c4 + 3][r] = a[3];
        }
        __syncthreads();

        f32x4 s[4];
        #pragma unroll
        for (int nt = 0; nt < 4; ++nt) {
            f32x4 acc = (f32x4){0.f, 0.f, 0.f, 0.f};
            #pragma unroll
            for (int kk = 0; kk < 3; ++kk) {
                short8 bf = *(short8*)&Ks[nt * 16 + l15][kk * 32 + quad * 8];
                acc = __builtin_amdgcn_mfma_f32_16x16x32_bf16(qf[kk], bf, acc, 0, 0, 0);
            }
            s[nt] = acc;
        }

        float alpha[4], rsum[4], mnew[4];
        #pragma unroll
        for (int r = 0; r < 4; ++r) {
            float tm = fmaxf(fmaxf(s[0][r], s[1][r]), fmaxf(s[2][r], s[3][r]));
            #pragma unroll
            for (int off = 1; off < 16; off <<= 1)
                tm = fmaxf(tm, __shfl_xor(tm, off, 64));
            mnew[r] = fmaxf(mrun[r], tm);
            alpha[r] = __expf(mrun[r] - mnew[r]);
            mrun[r] = mnew[r];
            rsum[r] = 0.f;
        }
        #pragma unroll
        for (int nt = 0; nt < 4; ++nt)
            #pragma unroll
            for (int r = 0; r < 4; ++r) {
                float p = __expf(s[nt][r] - mnew[r]);
                rsum[r] += p;
                Ps[w][quad * 4 + r][nt * 16 + l15] = f2bf(p);
            }
        #pragma unroll
        for (int r = 0; r < 4; ++r) {
            float rs = rsum[r];
            #pragma unroll
            for (int off = 1; off < 16; off <<= 1)
                rs += __shfl_xor(rs, off, 64);
            lrun[r] = lrun[r] * alpha[r] + rs;
        }
        #pragma unroll
        for (int n = 0; n < 5; ++n)
            #pragma unroll
            for (int r = 0; r < 4; ++r)
                o[n][r] *= alpha[r];

        short8 pf[2];
        #pragma unroll
        for (int kk = 0; kk < 2; ++kk)
            pf[kk] = *(short8*)&Ps[w][l15][kk * 32 + quad * 8];
        #pragma unroll
        for (int n = 0; n < 5; ++n)
            #pragma unroll
            for (int kk = 0; kk < 2; ++kk) {
                short8 vf = *(short8*)&Vts[n * 16 + l15][kk * 32 + quad * 8];
                o[n] = __builtin_amdgcn_mfma_f32_16x16x32_bf16(pf[kk], vf, o[n], 0, 0, 0);
            }
    }

    float inv[4];
    #pragma unroll
    for (int r = 0; r < 4; ++r) inv[r] = 1.f / lrun[r];
    #pragma unroll
    for (int n = 0; n < 5; ++n)
        #pragma unroll
        for (int r = 0; r < 4; ++r) {
            int row = q0 + w * 16 + quad * 4 + r;
            float ov = o[n][r] * inv[r];
            short hi = f2bf(ov);
            short lo = f2bf(ov - bf2f(hi));
            size_t idx = (size_t)row * DD + h * HDD + n * 16 + l15;
            out_hi[idx] = hi;
            out_lo[idx] = lo;
        }
}

extern "C" void kernel_launch(void* const* d_in, const int* in_sizes, int n_in,
                              void* d_out, int out_size, void* d_ws, size_t ws_size,
                              hipStream_t stream)
{
    const float* hs     = (const float*)d_in[0];
    const float* rpe    = (const float*)d_in[1];
    const float* qkv_w  = (const float*)d_in[2];
    const float* qkv_b  = (const float*)d_in[3];
    const float* proj_w = (const float*)d_in[4];
    const float* proj_b = (const float*)d_in[5];
    float* out = (float*)d_out;

    // ---- workspace layout (61.6 MB, region-aliased) ----
    short* s0 = (short*)d_ws;                 // R0: 15,728,640 shorts (qkv fp32)
    float* qkv_f   = (float*)d_ws;            //   [S][3D] fp32, dead after rope
    short* projw_hi = s0;                     //   R0 reuse after rope:
    short* projw_lo = s0 + 1638400;
    short* attn_hi  = s0 + 3276800;
    short* attn_lo  = s0 + 5898240;           //   ends at 8,519,680 < 15,728,640 ok
    short* s1 = s0 + 15728640;                // R1: 9,830,400 shorts
    short* qkvw_hi = s1;                      //   dead after gemm1
    short* qkvw_lo = s1 + 4915200;
    short* qb = s1;                           //   R1 reuse after gemm1:
    short* kb = s1 + 2621440;
    short* vb = s1 + 5242880;                 //   ends at 7,864,320 < 9,830,400 ok
    short* s2 = s1 + 9830400;                 // R2: 5,242,880 shorts
    short* hs_hi = s2;
    short* hs_lo = s2 + 2621440;

    const int n_hs = SS * DD;        // 2,621,440
    const int n_qw = ND3 * DD;       // 4,915,200
    const int n_pw = DD * DD;        // 1,638,400

    split_hl<<<n_hs / 1024, 256, 0, stream>>>(hs, hs_hi, hs_lo, n_hs);
    split_hl<<<n_qw / 1024, 256, 0, stream>>>(qkv_w, qkvw_hi, qkvw_lo, n_qw);
    gemm_bf16x3<128><<<dim3(ND3 / 128, SS / 128), 256, 0, stream>>>(
        hs_hi, hs_lo, qkvw_hi, qkvw_lo, qkv_b, qkv_f, SS, ND3, DD);
    rope_scatter_bf16<<<SS, 256, 0, stream>>>(qkv_f, rpe, qb, kb, vb);
    split_hl<<<n_pw / 1024, 256, 0, stream>>>(proj_w, projw_hi, projw_lo, n_pw);
    attn_mfma<<<dim3(SS / 64, HH), 256, 0, stream>>>(qb, kb, vb, attn_hi, attn_lo);
    gemm_bf16x3<64><<<dim3(DD / 64, SS / 128), 256, 0, stream>>>(
        attn_hi, attn_lo, projw_hi, projw_lo, proj_b, out, SS, DD, DD);
}

// Round 4
// 270.120 us; speedup vs baseline: 7.3861x; 1.1124x over previous
//
#include <hip/hip_runtime.h>
#include <math.h>

#define SS 2048
#define DD 1280
#define HH 16
#define HDD 80
#define ND3 3840

typedef __attribute__((ext_vector_type(8))) short short8;
typedef __attribute__((ext_vector_type(4))) short s16x4;
typedef __attribute__((ext_vector_type(4))) float f32x4;

__device__ inline short f2bf(float f) {
    union { float f; unsigned u; } x; x.f = f;
    unsigned r = x.u + 0x7FFF + ((x.u >> 16) & 1);
    return (short)(r >> 16);
}
__device__ inline float bf2f(short s) {
    union { unsigned u; float f; } x; x.u = ((unsigned)(unsigned short)s) << 16;
    return x.f;
}

// ---------------- split fp32 -> (hi, lo) bf16 ----------------
__global__ __launch_bounds__(256) void split_hl(
    const float* __restrict__ x, short* __restrict__ hi, short* __restrict__ lo, int n)
{
    int i = (blockIdx.x * 256 + threadIdx.x) * 4;
    if (i >= n) return;
    float4 v = *(const float4*)(x + i);
    s16x4 h, l;
    float vv[4] = {v.x, v.y, v.z, v.w};
    #pragma unroll
    for (int c = 0; c < 4; ++c) {
        short hh = f2bf(vv[c]);
        h[c] = hh;
        l[c] = f2bf(vv[c] - bf2f(hh));
    }
    *(s16x4*)(hi + i) = h;
    *(s16x4*)(lo + i) = l;
}

// ---------------- bf16x3 MFMA GEMM: C = A @ B^T + bias ----------------
#define LDSA(m, kg) ((m) * 32 + (((kg) ^ (((m) >> 1) & 3)) << 3))

template <int BNT>
__global__ __launch_bounds__(256) void gemm_bf16x3(
    const short* __restrict__ Ah, const short* __restrict__ Al,
    const short* __restrict__ Bh, const short* __restrict__ Bl,
    const float* __restrict__ bias, float* __restrict__ C,
    int M, int N, int K)
{
    constexpr int JT = BNT / 32;
    constexpr int BU = (BNT * 4) / 256;
    __shared__ short AhS[128 * 32];
    __shared__ short AlS[128 * 32];
    __shared__ short BhS[BNT * 32];
    __shared__ short BlS[BNT * 32];

    const int tid = threadIdx.x;
    const int w = tid >> 6;
    const int lane = tid & 63;
    const int l15 = lane & 15;
    const int quad = lane >> 4;
    const int wm = w >> 1, wn = w & 1;
    const int bm = blockIdx.y * 128;
    const int bn = blockIdx.x * BNT;

    f32x4 acc[4][JT];
    #pragma unroll
    for (int i = 0; i < 4; ++i)
        #pragma unroll
        for (int j = 0; j < JT; ++j)
            acc[i][j] = (f32x4){0.f, 0.f, 0.f, 0.f};

    short8 rah[2], ral[2], rbh[BU], rbl[BU];
    auto loadg = [&](int k0) {
        #pragma unroll
        for (int u = 0; u < 2; ++u) {
            int c = tid + u * 256, m = c >> 2, kg = c & 3;
            size_t off = (size_t)(bm + m) * K + k0 + kg * 8;
            rah[u] = *(const short8*)(Ah + off);
            ral[u] = *(const short8*)(Al + off);
        }
        #pragma unroll
        for (int u = 0; u < BU; ++u) {
            int c = tid + u * 256, m = c >> 2, kg = c & 3;
            size_t off = (size_t)(bn + m) * K + k0 + kg * 8;
            rbh[u] = *(const short8*)(Bh + off);
            rbl[u] = *(const short8*)(Bl + off);
        }
    };

    loadg(0);
    for (int k0 = 0; k0 < K; k0 += 32) {
        __syncthreads();
        #pragma unroll
        for (int u = 0; u < 2; ++u) {
            int c = tid + u * 256, m = c >> 2, kg = c & 3;
            *(short8*)&AhS[LDSA(m, kg)] = rah[u];
            *(short8*)&AlS[LDSA(m, kg)] = ral[u];
        }
        #pragma unroll
        for (int u = 0; u < BU; ++u) {
            int c = tid + u * 256, m = c >> 2, kg = c & 3;
            *(short8*)&BhS[LDSA(m, kg)] = rbh[u];
            *(short8*)&BlS[LDSA(m, kg)] = rbl[u];
        }
        __syncthreads();
        if (k0 + 32 < K) loadg(k0 + 32);

        short8 af[4], alf[4], bfh[JT], bfl[JT];
        #pragma unroll
        for (int i = 0; i < 4; ++i) {
            int m = wm * 64 + i * 16 + l15;
            af[i]  = *(short8*)&AhS[LDSA(m, quad)];
            alf[i] = *(short8*)&AlS[LDSA(m, quad)];
        }
        #pragma unroll
        for (int j = 0; j < JT; ++j) {
            int n = wn * (BNT / 2) + j * 16 + l15;
            bfh[j] = *(short8*)&BhS[LDSA(n, quad)];
            bfl[j] = *(short8*)&BlS[LDSA(n, quad)];
        }
        #pragma unroll
        for (int i = 0; i < 4; ++i)
            #pragma unroll
            for (int j = 0; j < JT; ++j) {
                acc[i][j] = __builtin_amdgcn_mfma_f32_16x16x32_bf16(af[i],  bfh[j], acc[i][j], 0, 0, 0);
                acc[i][j] = __builtin_amdgcn_mfma_f32_16x16x32_bf16(af[i],  bfl[j], acc[i][j], 0, 0, 0);
                acc[i][j] = __builtin_amdgcn_mfma_f32_16x16x32_bf16(alf[i], bfh[j], acc[i][j], 0, 0, 0);
            }
    }

    #pragma unroll
    for (int j = 0; j < JT; ++j) {
        int col = bn + wn * (BNT / 2) + j * 16 + l15;
        float bb = bias[col];
        #pragma unroll
        for (int i = 0; i < 4; ++i)
            #pragma unroll
            for (int r = 0; r < 4; ++r) {
                int row = bm + wm * 64 + i * 16 + quad * 4 + r;
                C[(size_t)row * N + col] = acc[i][j][r] + bb;
            }
    }
}

// ---------------- RoPE + scatter -> bf16 q (pre-scaled), k, v ----------------
__global__ __launch_bounds__(256) void rope_scatter_bf16(
    const float* __restrict__ qkv, const float* __restrict__ rpe,
    short* __restrict__ q, short* __restrict__ k, short* __restrict__ v)
{
    __shared__ float cs[40], sn[40];
    const int s = blockIdx.x;
    if (threadIdx.x < 40)
        __sincosf(rpe[s * 40 + threadIdx.x], &sn[threadIdx.x], &cs[threadIdx.x]);
    __syncthreads();
    const float scale = 0.11180339887498949f;  // 80^-0.5
    for (int j = threadIdx.x; j < ND3; j += 256) {
        int p = j / DD;
        int rem = j - p * DD;
        int hh = rem / HDD;
        int d = rem - hh * HDD;
        float x = qkv[(size_t)s * ND3 + j];
        float val;
        if (p == 2) {
            val = x;
        } else {
            int dm = (d < 40) ? d : d - 40;
            float other = (d < 40)
                ? -qkv[(size_t)s * ND3 + p * DD + hh * HDD + d + 40]
                :  qkv[(size_t)s * ND3 + p * DD + hh * HDD + d - 40];
            val = x * cs[dm] + other * sn[dm];
            if (p == 0) val *= scale;
        }
        short* dst = (p == 0) ? q : (p == 1) ? k : v;
        dst[((size_t)hh * SS + s) * HDD + d] = f2bf(val);
    }
}

// ---------------- flash attention, bf16 MFMA, fixed-max softmax, K-split ------
// exp(s - 16): softmax max cancels exactly; |s| <= |q||k|/sqrt(80) << 104 so no
// overflow; p ~ 1e-6 keeps full bf16/fp32 relative precision. Partials (o, l)
// merge by plain addition.
__global__ __launch_bounds__(256) void attn_mfma(
    const short* __restrict__ q, const short* __restrict__ k,
    const short* __restrict__ v, float* __restrict__ o_part,
    float* __restrict__ l_part)
{
    __shared__ short Ks[64][104];    // k-positions x d, pad cols 80..95 zeroed
    __shared__ short Vts[80][72];    // d x k-positions (transposed V)
    __shared__ short Ps[4][16][72];  // per-wave P tile

    const int h = blockIdx.y;
    const int q0 = blockIdx.x << 6;
    const int z = blockIdx.z;        // K-half: keys [z*1024, z*1024+1024)
    const int tid = threadIdx.x;
    const int w = tid >> 6;
    const int lane = tid & 63;
    const int l15 = lane & 15;
    const int quad = lane >> 4;

    const short* qbase = q + (size_t)h * SS * HDD;
    const short* kbase = k + (size_t)h * SS * HDD;
    const short* vbase = v + (size_t)h * SS * HDD;

    short8 qf[3];
    {
        const int row = q0 + w * 16 + l15;
        #pragma unroll
        for (int kk = 0; kk < 3; ++kk) {
            int c0 = kk * 32 + quad * 8;
            qf[kk] = (c0 < HDD) ? *(const short8*)(qbase + (size_t)row * HDD + c0)
                                : (short8)0;
        }
    }

    if (tid < 128) {  // zero K pad cols 80..95
        int r = tid >> 1, c = 80 + (tid & 1) * 8;
        *(short8*)&Ks[r][c] = (short8)0;
    }

    float lsum[4] = {0.f, 0.f, 0.f, 0.f};
    f32x4 o[5];
    #pragma unroll
    for (int n = 0; n < 5; ++n) o[n] = (f32x4){0.f, 0.f, 0.f, 0.f};

    const int kt0 = z << 10;
    for (int kt = kt0; kt < kt0 + 1024; kt += 64) {
        __syncthreads();
        // ---- stage K tile (coalesced short8) ----
        #pragma unroll
        for (int u = 0; u < 3; ++u) {
            int i = tid + u * 256;
            if (i < 640) {
                int r = i / 10, c = (i - r * 10) * 8;
                *(short8*)&Ks[r][c] = *(const short8*)(kbase + (size_t)(kt + r) * HDD + c);
            }
        }
        // ---- stage V transposed via 4x4 blocks (8B LDS writes) ----
        #pragma unroll
        for (int u = 0; u < 2; ++u) {
            int task = tid + u * 256;
            if (task < 320) {
                int r4 = (task & 15) << 2, d4 = (task >> 4) << 2;
                s16x4 a0 = *(const s16x4*)(vbase + (size_t)(kt + r4 + 0) * HDD + d4);
                s16x4 a1 = *(const s16x4*)(vbase + (size_t)(kt + r4 + 1) * HDD + d4);
                s16x4 a2 = *(const s16x4*)(vbase + (size_t)(kt + r4 + 2) * HDD + d4);
                s16x4 a3 = *(const s16x4*)(vbase + (size_t)(kt + r4 + 3) * HDD + d4);
                #pragma unroll
                for (int j = 0; j < 4; ++j) {
                    s16x4 w4 = {a0[j], a1[j], a2[j], a3[j]};
                    *(s16x4*)&Vts[d4 + j][r4] = w4;
                }
            }
        }
        __syncthreads();

        // ---- QK^T ----
        f32x4 s_[4];
        #pragma unroll
        for (int nt = 0; nt < 4; ++nt) {
            f32x4 acc = (f32x4){0.f, 0.f, 0.f, 0.f};
            #pragma unroll
            for (int kk = 0; kk < 3; ++kk) {
                short8 bf = *(short8*)&Ks[nt * 16 + l15][kk * 32 + quad * 8];
                acc = __builtin_amdgcn_mfma_f32_16x16x32_bf16(qf[kk], bf, acc, 0, 0, 0);
            }
            s_[nt] = acc;
        }

        // ---- p = exp(s - 16), per-lane partial sums, P -> LDS ----
        #pragma unroll
        for (int nt = 0; nt < 4; ++nt)
            #pragma unroll
            for (int r = 0; r < 4; ++r) {
                float p = __expf(s_[nt][r] - 16.f);
                lsum[r] += p;
                Ps[w][quad * 4 + r][nt * 16 + l15] = f2bf(p);
            }

        // ---- P (C-layout) -> A-operand via LDS, then PV ----
        short8 pf[2];
        #pragma unroll
        for (int kk = 0; kk < 2; ++kk)
            pf[kk] = *(short8*)&Ps[w][l15][kk * 32 + quad * 8];
        #pragma unroll
        for (int n = 0; n < 5; ++n)
            #pragma unroll
            for (int kk = 0; kk < 2; ++kk) {
                short8 vf = *(short8*)&Vts[n * 16 + l15][kk * 32 + quad * 8];
                o[n] = __builtin_amdgcn_mfma_f32_16x16x32_bf16(pf[kk], vf, o[n], 0, 0, 0);
            }
    }

    // ---- one deferred l-reduction across the 16-lane col groups ----
    #pragma unroll
    for (int r = 0; r < 4; ++r) {
        float rs = lsum[r];
        #pragma unroll
        for (int off = 1; off < 16; off <<= 1)
            rs += __shfl_xor(rs, off, 64);
        lsum[r] = rs;
    }

    float* ob = o_part + (size_t)z * SS * DD;
    #pragma unroll
    for (int n = 0; n < 5; ++n)
        #pragma unroll
        for (int r = 0; r < 4; ++r) {
            int row = q0 + w * 16 + quad * 4 + r;
            ob[(size_t)row * DD + h * HDD + n * 16 + l15] = o[n][r];
        }
    if (l15 == 0)
        #pragma unroll
        for (int r = 0; r < 4; ++r)
            l_part[((size_t)z * HH + h) * SS + q0 + w * 16 + quad * 4 + r] = lsum[r];
}

// ---------------- merge K-split halves, emit hi/lo bf16 ----------------
__global__ __launch_bounds__(256) void attn_merge(
    const float* __restrict__ o_part, const float* __restrict__ l_part,
    short* __restrict__ hi, short* __restrict__ lo)
{
    int i = (blockIdx.x * 256 + threadIdx.x) * 4;
    int row = i / DD;
    int col = i - row * DD;
    int h = col / HDD;
    float4 a = *(const float4*)(o_part + i);
    float4 b = *(const float4*)(o_part + (size_t)SS * DD + i);
    float l = l_part[h * SS + row] + l_part[(HH + h) * SS + row];
    float inv = 1.f / l;
    float vv[4] = {a.x + b.x, a.y + b.y, a.z + b.z, a.w + b.w};
    s16x4 vh, vl;
    #pragma unroll
    for (int c = 0; c < 4; ++c) {
        float ov = vv[c] * inv;
        short hh = f2bf(ov);
        vh[c] = hh;
        vl[c] = f2bf(ov - bf2f(hh));
    }
    *(s16x4*)(hi + i) = vh;
    *(s16x4*)(lo + i) = vl;
}

extern "C" void kernel_launch(void* const* d_in, const int* in_sizes, int n_in,
                              void* d_out, int out_size, void* d_ws, size_t ws_size,
                              hipStream_t stream)
{
    const float* hs     = (const float*)d_in[0];
    const float* rpe    = (const float*)d_in[1];
    const float* qkv_w  = (const float*)d_in[2];
    const float* qkv_b  = (const float*)d_in[3];
    const float* proj_w = (const float*)d_in[4];
    const float* proj_b = (const float*)d_in[5];
    float* out = (float*)d_out;

    // ---- workspace layout (61.6 MB, region-aliased) ----
    short* s0 = (short*)d_ws;                 // R0: 15,728,640 shorts = 7,864,320 floats
    float* qkv_f  = (float*)d_ws;             //   [S][3D] fp32, dead after rope
    float* o_part = (float*)d_ws;             //   R0 reuse: 2 x S x D partial O
    float* l_part = (float*)d_ws + 5242880;   //   2 x H x S partial l (65,536 floats)
    short* s1 = s0 + 15728640;                // R1: 9,830,400 shorts
    short* qkvw_hi = s1;                      //   dead after gemm1
    short* qkvw_lo = s1 + 4915200;
    short* qb = s1;                           //   R1 reuse after gemm1 (dead after attn)
    short* kb = s1 + 2621440;
    short* vb = s1 + 5242880;
    short* attn_hi = s1;                      //   R1 reuse after attn (merge writes)
    short* attn_lo = s1 + 2621440;
    short* s2 = s1 + 9830400;                 // R2: 5,242,880 shorts
    short* hs_hi = s2;                        //   dead after gemm1
    short* hs_lo = s2 + 2621440;
    short* projw_hi = s2;                     //   R2 reuse after gemm1
    short* projw_lo = s2 + 1638400;

    const int n_hs = SS * DD;        // 2,621,440
    const int n_qw = ND3 * DD;       // 4,915,200
    const int n_pw = DD * DD;        // 1,638,400

    split_hl<<<n_hs / 1024, 256, 0, stream>>>(hs, hs_hi, hs_lo, n_hs);
    split_hl<<<n_qw / 1024, 256, 0, stream>>>(qkv_w, qkvw_hi, qkvw_lo, n_qw);
    gemm_bf16x3<128><<<dim3(ND3 / 128, SS / 128), 256, 0, stream>>>(
        hs_hi, hs_lo, qkvw_hi, qkvw_lo, qkv_b, qkv_f, SS, ND3, DD);
    rope_scatter_bf16<<<SS, 256, 0, stream>>>(qkv_f, rpe, qb, kb, vb);
    split_hl<<<n_pw / 1024, 256, 0, stream>>>(proj_w, projw_hi, projw_lo, n_pw);
    attn_mfma<<<dim3(SS / 64, HH, 2), 256, 0, stream>>>(qb, kb, vb, o_part, l_part);
    attn_merge<<<(SS * DD) / 1024, 256, 0, stream>>>(o_part, l_part, attn_hi, attn_lo);
    gemm_bf16x3<64><<<dim3(DD / 64, SS / 128), 256, 0, stream>>>(
        attn_hi, attn_lo, projw_hi, projw_lo, proj_b, out, SS, DD, DD);
}